// Round 10
// baseline (170.081 us; speedup 1.0000x reference)
//
#include <hip/hip_runtime.h>
#include <hip/hip_bf16.h>

// Problem constants
#define BATCH 2
#define SEQ   2048
#define CDIM  768
#define HEADS 12
#define DHEAD 64
#define QKV_N 2304   // 3*CDIM
#define ROWS  4096   // BATCH*SEQ

typedef unsigned short u16;
typedef unsigned int   u32;
typedef __attribute__((ext_vector_type(4))) float f32x4;
typedef __attribute__((ext_vector_type(8))) short bf16x8;
typedef __attribute__((ext_vector_type(2))) unsigned int u32x2;

// fp32 -> bf16 (RNE) bit pattern
__device__ __forceinline__ u16 f2b(float f) {
    union { float f; unsigned u; } v; v.f = f;
    unsigned r = v.u + 0x7FFF + ((v.u >> 16) & 1u);
    return (u16)(r >> 16);
}
// bf16 bits -> fp32
__device__ __forceinline__ float b2f(u16 u) {
    union { unsigned i; float f; } x;
    x.i = ((unsigned)u) << 16;
    return x.f;
}
// pack two fp32 -> one u32 of 2x bf16 (RNE), single VALU instruction.
__device__ __forceinline__ u32 cvt_pk_bf16(float lo, float hi) {
    u32 r;
    asm("v_cvt_pk_bf16_f32 %0, %1, %2" : "=v"(r) : "v"(lo), "v"(hi));
    return r;
}

// exp2: native v_exp_f32 when builtin available
#if __has_builtin(__builtin_amdgcn_exp2f)
#define EXP2(x) __builtin_amdgcn_exp2f(x)
#else
#define EXP2(x) __expf((x) * 0.69314718056f)
#endif

// async global->LDS 16B copy
__device__ __forceinline__ void load_lds16(const void* g, void* l) {
    __builtin_amdgcn_global_load_lds(
        (const __attribute__((address_space(1))) u32*)g,
        (__attribute__((address_space(3))) u32*)l, 16, 0, 0);
}

// ---------------------------------------------------------------------------
// Fused prep: x->bf16 (blocks [0,3072)), qkv_w transpose-convert
// (blocks [3072,4800)), proj_w transpose-convert (blocks [4800,5376)).
// ---------------------------------------------------------------------------
#define PREP_CONV 3072          // 4096*768/4 float4 / 256
#define PREP_TQ   1728          // (2304/32) x (768/32)
#define PREP_TP   576           // (768/32) x (768/32)

__device__ __forceinline__ void tconv_body(
    const float* __restrict__ in, u16* __restrict__ out, int R, int C,
    int bi, int bj)
{
    __shared__ float t[32][33];
    const int c = threadIdx.x & 31, r0 = threadIdx.x >> 5;
    #pragma unroll
    for (int i = 0; i < 4; i++) {
        const int r = r0 + i * 8;
        t[r][c] = in[(size_t)(bi * 32 + r) * C + bj * 32 + c];
    }
    __syncthreads();
    #pragma unroll
    for (int i = 0; i < 4; i++) {
        const int r = r0 + i * 8;
        out[(size_t)(bj * 32 + r) * R + bi * 32 + c] = f2b(t[c][r]);
    }
}

__global__ __launch_bounds__(256) void prep_kernel(
    const float* __restrict__ x, u16* __restrict__ xb,
    const float* __restrict__ qkv_w, u16* __restrict__ wT,
    const float* __restrict__ proj_w, u16* __restrict__ pwT)
{
    const int bid = blockIdx.x;
    if (bid < PREP_CONV) {
        const int i = bid * 256 + threadIdx.x;
        const float4 v = reinterpret_cast<const float4*>(x)[i];
        ushort4 o;
        o.x = f2b(v.x); o.y = f2b(v.y); o.z = f2b(v.z); o.w = f2b(v.w);
        reinterpret_cast<ushort4*>(xb)[i] = o;
    } else if (bid < PREP_CONV + PREP_TQ) {
        const int t = bid - PREP_CONV;
        tconv_body(qkv_w, wT, CDIM, QKV_N, t / 72, t % 72);
    } else {
        const int t = bid - PREP_CONV - PREP_TQ;
        tconv_body(proj_w, pwT, CDIM, CDIM, t / 24, t % 24);
    }
}

// ---------------------------------------------------------------------------
// bf16 MFMA GEMM 128x128 BK32, DOUBLE-BUFFERED LDS (1 barrier/K-step),
// + FUSED RMSNorm + RoPE epilogue. q pre-scaled by Dh^-0.5 * log2(e).
// 1-D grid (576 blocks) with XCD-aware swizzle: 576%8==0, bijective remap.
// V6: RoPE-PAIR COLUMN PERMUTATION (partners in-register, packed u32 stores).
// ---------------------------------------------------------------------------
__device__ __forceinline__ int bperm(int row) {
    const int p = row & 63;
    const int j = p >> 4, l = p & 15;
    return (row & ~63) | ((j & 1) + 2 * l + 32 * (j >> 1));
}

__global__ __launch_bounds__(256) void gemm_qkv_mfma_kernel(
    const u16* __restrict__ A, int lda,
    const u16* __restrict__ BT,
    const float* __restrict__ bias,
    const float* __restrict__ cosb, const float* __restrict__ sinb,
    const float* __restrict__ qn, const float* __restrict__ kn,
    u16* __restrict__ C, int ldc, int K)
{
    __shared__ u16 sA[2][128 * 32];
    __shared__ u16 sB[2][128 * 32];
    const int tid = threadIdx.x;
    const int lane = tid & 63;
    const int wave = tid >> 6;
    const int wy = wave >> 1, wx = wave & 1;
    const int l16 = lane & 15, quad = lane >> 4;

    // XCD swizzle: consecutive ids round-robin XCDs; give each XCD a
    // contiguous chunk of tile space (72 tiles = 4 m-rows) for L2 locality.
    int id = blockIdx.x;
    id = (id & 7) * 72 + (id >> 3);        // 576/8 = 72
    const int m0 = (id / 18) * 128, n0 = (id % 18) * 128;

    // staging indices (2 granules each of A and B per thread)
    const int srow0 = tid >> 2,         sg0 = tid & 3;
    const int srow1 = (tid + 256) >> 2, sg1 = tid & 3;   // f = tid+256

    // permuted B source rows (RoPE-pair layout)
    const int brow0 = bperm(n0 + srow0);
    const int brow1 = bperm(n0 + srow1);

    f32x4 acc[4][4] = {};
    const int NK = K / 32;

    // prologue: stage k-step 0 into buffer 0
    load_lds16(A  + (size_t)(m0 + srow0) * lda + sg0 * 8, &sA[0][tid * 8]);
    load_lds16(BT + (size_t)brow0 * K          + sg0 * 8, &sB[0][tid * 8]);
    load_lds16(A  + (size_t)(m0 + srow1) * lda + sg1 * 8, &sA[0][(tid + 256) * 8]);
    load_lds16(BT + (size_t)brow1 * K          + sg1 * 8, &sB[0][(tid + 256) * 8]);

    for (int kt = 0; kt < NK; kt++) {
        const int cur = kt & 1;
        __syncthreads();   // DMA into buf[cur] complete; prior reads of buf[cur^1] done
        if (kt + 1 < NK) {
            const int nxt = cur ^ 1;
            const int k0 = (kt + 1) * 32;
            load_lds16(A  + (size_t)(m0 + srow0) * lda + k0 + sg0 * 8, &sA[nxt][tid * 8]);
            load_lds16(BT + (size_t)brow0 * K          + k0 + sg0 * 8, &sB[nxt][tid * 8]);
            load_lds16(A  + (size_t)(m0 + srow1) * lda + k0 + sg1 * 8, &sA[nxt][(tid + 256) * 8]);
            load_lds16(BT + (size_t)brow1 * K          + k0 + sg1 * 8, &sB[nxt][(tid + 256) * 8]);
        }

        bf16x8 af[4], bfr[4];
        #pragma unroll
        for (int i = 0; i < 4; i++) {
            af[i]  = *reinterpret_cast<const bf16x8*>(
                &sA[cur][(wy * 64 + i * 16 + l16) * 32 + quad * 8]);
            bfr[i] = *reinterpret_cast<const bf16x8*>(
                &sB[cur][(wx * 64 + i * 16 + l16) * 32 + quad * 8]);
        }
        #pragma unroll
        for (int i = 0; i < 4; i++)
            #pragma unroll
            for (int j = 0; j < 4; j++)
                acc[i][j] = __builtin_amdgcn_mfma_f32_16x16x32_bf16(
                    af[i], bfr[j], acc[i][j], 0, 0, 0);
    }

    // ---- fused epilogue (thread holds logical cols 2*l16,2*l16+1,32+2*l16,33+2*l16) ----
    const int cb = (n0 + wx * 64) >> 6;   // 64-col block, 0..35
    const int s  = cb / 12;               // 0=q, 1=k, 2=v
    const int colbase = n0 + wx * 64;
    // logical col offsets within head for j=0..3
    const int d0 = 2 * l16, d1 = 2 * l16 + 1, d2 = 2 * l16 + 32, d3 = 2 * l16 + 33;
    float bv[4];
    bv[0] = bias[colbase + d0]; bv[1] = bias[colbase + d1];
    bv[2] = bias[colbase + d2]; bv[3] = bias[colbase + d3];
    float wv[4];
    if (s < 2) {
        const float* wn = (s == 0) ? qn : kn;
        wv[0] = wn[d0]; wv[1] = wn[d1]; wv[2] = wn[d2]; wv[3] = wn[d3];
    }

    #pragma unroll
    for (int i = 0; i < 4; i++) {
        #pragma unroll
        for (int r = 0; r < 4; r++) {
            const int row = m0 + wy * 64 + i * 16 + quad * 4 + r;
            float v[4];
            #pragma unroll
            for (int j = 0; j < 4; j++) v[j] = acc[i][j][r] + bv[j];

            if (s < 2) {
                float sq = v[0]*v[0] + v[1]*v[1] + v[2]*v[2] + v[3]*v[3];
                #pragma unroll
                for (int off = 1; off < 16; off <<= 1)
                    sq += __shfl_xor(sq, off, 64);
                const float rms = rsqrtf(sq * (1.0f / 64.0f) + 1e-6f);
                const int n = row & (SEQ - 1);
                const float nv0 = v[0] * rms * wv[0];
                const float nv1 = v[1] * rms * wv[1];
                const float nv2 = v[2] * rms * wv[2];
                const float nv3 = v[3] * rms * wv[3];
                const float c0 = cosb[n * 32 + l16],      s0 = sinb[n * 32 + l16];
                const float c1 = cosb[n * 32 + 16 + l16], s1 = sinb[n * 32 + 16 + l16];
                v[0] = nv0 * c0 - nv1 * s0;
                v[1] = nv0 * s0 + nv1 * c0;
                v[2] = nv2 * c1 - nv3 * s1;
                v[3] = nv2 * s1 + nv3 * c1;
                if (s == 0) {
                    // fold Dh^-0.5 * log2(e) into q: scores land in exp2 domain
                    v[0] *= 0.18033688011112042f; v[1] *= 0.18033688011112042f;
                    v[2] *= 0.18033688011112042f; v[3] *= 0.18033688011112042f;
                }
            }
            u32* cw = reinterpret_cast<u32*>(&C[(size_t)row * ldc + colbase]);
            cw[l16]      = cvt_pk_bf16(v[0], v[1]);   // u16 cols 2*l16, 2*l16+1
            cw[16 + l16] = cvt_pk_bf16(v[2], v[3]);   // u16 cols 32+2*l16, 33+2*l16
        }
    }
}

// ---------------------------------------------------------------------------
// bf16 MFMA GEMM 64x64 BK32, double-buffered, fp32 output + bias.
// 1-D grid (768 blocks) with XCD-aware swizzle (768%8==0, bijective).
// ---------------------------------------------------------------------------
__global__ __launch_bounds__(256) void gemm_proj_mfma_kernel(
    const u16* __restrict__ A, int lda,
    const u16* __restrict__ BT,
    const float* __restrict__ bias,
    float* __restrict__ C, int ldc, int K)
{
    __shared__ u16 sA[2][64 * 32];
    __shared__ u16 sB[2][64 * 32];
    const int tid = threadIdx.x;
    const int lane = tid & 63;
    const int wave = tid >> 6;
    const int l16 = lane & 15, quad = lane >> 4;

    int id = blockIdx.x;
    id = (id & 7) * 96 + (id >> 3);        // 768/8 = 96
    const int m0 = (id / 12) * 64, n0 = (id % 12) * 64;

    const int srow = tid >> 2, sg = tid & 3;   // 256 granules per matrix

    f32x4 acc[4] = {};
    const int NK = K / 32;

    load_lds16(A  + (size_t)(m0 + srow) * lda + sg * 8, &sA[0][tid * 8]);
    load_lds16(BT + (size_t)(n0 + srow) * K   + sg * 8, &sB[0][tid * 8]);

    for (int kt = 0; kt < NK; kt++) {
        const int cur = kt & 1;
        __syncthreads();
        if (kt + 1 < NK) {
            const int nxt = cur ^ 1;
            const int k0 = (kt + 1) * 32;
            load_lds16(A  + (size_t)(m0 + srow) * lda + k0 + sg * 8, &sA[nxt][tid * 8]);
            load_lds16(BT + (size_t)(n0 + srow) * K   + k0 + sg * 8, &sB[nxt][tid * 8]);
        }

        const bf16x8 af = *reinterpret_cast<const bf16x8*>(
            &sA[cur][(wave * 16 + l16) * 32 + quad * 8]);
        bf16x8 bfr[4];
        #pragma unroll
        for (int j = 0; j < 4; j++)
            bfr[j] = *reinterpret_cast<const bf16x8*>(
                &sB[cur][(j * 16 + l16) * 32 + quad * 8]);
        #pragma unroll
        for (int j = 0; j < 4; j++)
            acc[j] = __builtin_amdgcn_mfma_f32_16x16x32_bf16(
                af, bfr[j], acc[j], 0, 0, 0);
    }

    float bv[4];
    #pragma unroll
    for (int j = 0; j < 4; j++) bv[j] = bias[n0 + j * 16 + l16];
    #pragma unroll
    for (int r = 0; r < 4; r++) {
        const int row = m0 + wave * 16 + quad * 4 + r;
        #pragma unroll
        for (int j = 0; j < 4; j++) {
            const int col = n0 + j * 16 + l16;
            C[(size_t)row * ldc + col] = acc[j][r] + bv[j];
        }
    }
}

// ---------------------------------------------------------------------------
// Flash MFMA attention V11 = V10 (8-wave key-split + permlane P) with
// K STAGING VIA global_load_lds (DMA): global->LDS direct, no VGPR round
// trip, no ds_write issue (-96 cyc/tile/block LDS issue), kreg freed.
// Swizzle preserved via PRE-SWIZZLED GLOBAL SOURCE (m173 pattern): LDS dest
// is linear tid*16B (the DMA's wave-uniform+lane*16 form, 512thr x 16B =
// exactly the 8KB tile); lane (kq,g) fetches source granule g^(kq&7), which
// lands each granule where the old ds_write put it -> QK reads unchanged,
// bitwise-identical. Schedule per m97: DMA for tile t+1 issued AFTER the
// barrier (full compute phase to land, drained by the NEXT barrier); V
// reg-prefetch stays pre-barrier (R5/R6 A/B).
// ---------------------------------------------------------------------------
__global__ __launch_bounds__(512) void attn_mfma_kernel(u16* __restrict__ qkvb)
{
    const int qt = blockIdx.x;   // q tile (64 rows)
    const int h  = blockIdx.y;
    const int b  = blockIdx.z;
    const int tid  = threadIdx.x;
    const int wave = tid >> 6;        // 0..7
    const int wq   = wave & 3;        // q-row group
    const int w4   = wave >> 2;       // key-half (0: keys 0-31, 1: keys 32-63)
    const int lane = tid & 63;
    const int l16  = lane & 15;
    const int quad = lane >> 4;

    const size_t bb = (size_t)b * SEQ * QKV_N;
    const u16* Kg = qkvb + bb + CDIM     + h * DHEAD;
    const u16* Vg = qkvb + bb + 2 * CDIM + h * DHEAD;
    const u16* Qg = qkvb + bb + (size_t)(qt * 64) * QKV_N + h * DHEAD;

    __shared__ u16 sK[2][64 * 64];   // granule-XOR swizzled (via source), linear dest
    __shared__ u32 sVt32[2][64 * 32];

    // staging: 512 threads stage one K row-granule each; V rows in pairs, d-split
    const int kq = tid >> 3;          // K row 0..63
    const int g  = tid & 7;           // 16B granule (d = g*8..g*8+7)
    const int kp = (tid >> 3) & 31;   // V key pair: rows 2kp, 2kp+1
    const int e0 = (tid >> 8) * 4;    // d-subrange within granule: 0..3 or 4..7

    // pre-swizzled K source offset: fetch granule g^(kq&7) into linear slot g
    const int ksrc = (g ^ (kq & 7)) * 8;

    bf16x8 qf[2];
    {
        const u16* qrow = Qg + (size_t)(wq * 16 + l16) * QKV_N;
        qf[0] = *reinterpret_cast<const bf16x8*>(qrow + quad * 8);
        qf[1] = *reinterpret_cast<const bf16x8*>(qrow + 32 + quad * 8);
    }

    f32x4 O[4] = {};        // O^T partial (this wave's key-half): rows d, cols q
    float l_acc = 0.f;

    u32x2 vreg0, vreg1;
    // prologue: K tile 0 via DMA; V tile 0 into regs
    load_lds16(Kg + (size_t)kq * QKV_N + ksrc, &sK[0][tid * 8]);
    vreg0 = *reinterpret_cast<const u32x2*>(Vg + (size_t)(2 * kp)     * QKV_N + g * 8 + e0);
    vreg1 = *reinterpret_cast<const u32x2*>(Vg + (size_t)(2 * kp + 1) * QKV_N + g * 8 + e0);

    const int ks = l16 & 7;           // read-side row swizzle key

    const int NT = SEQ / 64;
    for (int t = 0; t < NT; t++) {
        const int cur = t & 1;
        // V stage from prefetched regs into sVt32[cur]
        const int pwv = kp ^ (4 * g) ^ ((g & 1) << 4);
        {
            const u32* v0w = reinterpret_cast<const u32*>(&vreg0);
            const u32* v1w = reinterpret_cast<const u32*>(&vreg1);
            #pragma unroll
            for (int el = 0; el < 4; el++) {
                const u32 pack = __builtin_amdgcn_perm(
                    v1w[el >> 1], v0w[el >> 1],
                    (el & 1) ? 0x07060302u : 0x05040100u);
                sVt32[cur][(g * 8 + e0 + el) * 32 + pwv] = pack;
            }
        }
        // V prefetch t+1 (pre-barrier, R5-proven slot)
        if (t + 1 < NT) {
            const size_t base = (size_t)(t + 1) * 64;
            vreg0 = *reinterpret_cast<const u32x2*>(Vg + (base + 2 * kp)     * QKV_N + g * 8 + e0);
            vreg1 = *reinterpret_cast<const u32x2*>(Vg + (base + 2 * kp + 1) * QKV_N + g * 8 + e0);
        }
        __syncthreads();   // K DMA(cur) complete; sK[nxt] readers (iter t-1) done

        // K DMA for tile t+1 -> sK[nxt] (post-barrier, m97 pattern:
        // full compute phase to land, drained by the next barrier)
        if (t + 1 < NT) {
            const size_t base = (size_t)(t + 1) * 64;
            load_lds16(Kg + (base + kq) * QKV_N + ksrc, &sK[cur ^ 1][tid * 8]);
        }

        // S^T for this wave's key-half: kt = w4*2 + i
        f32x4 s[2];
        __builtin_amdgcn_s_setprio(1);
        #pragma unroll
        for (int i = 0; i < 2; i++) {
            const int krow = (w4 * 2 + i) * 16 + l16;
            bf16x8 kf0 = *reinterpret_cast<const bf16x8*>(
                &sK[cur][krow * 64 + ((quad ^ ks) * 8)]);
            bf16x8 kf1 = *reinterpret_cast<const bf16x8*>(
                &sK[cur][krow * 64 + (((quad + 4) ^ ks) * 8)]);
            f32x4 a = {};
            a = __builtin_amdgcn_mfma_f32_16x16x32_bf16(kf0, qf[0], a, 0, 0, 0);
            a = __builtin_amdgcn_mfma_f32_16x16x32_bf16(kf1, qf[1], a, 0, 0, 0);
            s[i] = a;
        }
        __builtin_amdgcn_s_setprio(0);

        // P = exp2(S); l_acc in the same order as before (i=0 then i=1)
        u32 ax, ay, bx, by;
        {
            float p0 = EXP2(s[0][0]);
            float p1 = EXP2(s[0][1]);
            float p2 = EXP2(s[0][2]);
            float p3 = EXP2(s[0][3]);
            l_acc += p0; l_acc += p1; l_acc += p2; l_acc += p3;
            ax = cvt_pk_bf16(p0, p1);
            ay = cvt_pk_bf16(p2, p3);
        }
        {
            float p0 = EXP2(s[1][0]);
            float p1 = EXP2(s[1][1]);
            float p2 = EXP2(s[1][2]);
            float p3 = EXP2(s[1][3]);
            l_acc += p0; l_acc += p1; l_acc += p2; l_acc += p3;
            bx = cvt_pk_bf16(p0, p1);
            by = cvt_pk_bf16(p2, p3);
        }
        // in-register quad exchange (replaces sP2 write+read):
        asm("v_permlane32_swap_b32 %0, %1" : "+v"(ax), "+v"(bx));
        asm("v_permlane32_swap_b32 %0, %1" : "+v"(ay), "+v"(by));
        asm("v_permlane16_swap_b32 %0, %1" : "+v"(ax), "+v"(bx));
        asm("v_permlane16_swap_b32 %0, %1" : "+v"(ay), "+v"(by));

        union { struct { u32x2 lo, hi; } s2; bf16x8 v; } pu;
        pu.s2.lo.x = ax; pu.s2.lo.y = ay;   // keys w4*32+quad*8 .. +3
        pu.s2.hi.x = bx; pu.s2.hi.y = by;   // keys w4*32+quad*8+4 .. +7

        // O^T += V^T P^T over this wave's 32 keys (1 MFMA per dt)
        __builtin_amdgcn_s_setprio(1);
        #pragma unroll
        for (int dt = 0; dt < 4; dt++) {
            const int row = dt * 16 + l16;
            const int hr  = (row >> 3) & 7;
            const int sw  = (4 * hr) ^ ((hr & 1) << 4);
            bf16x8 vf = *reinterpret_cast<const bf16x8*>(
                &sVt32[cur][row * 32 + ((w4 * 16 + quad * 4) ^ sw)]);
            O[dt] = __builtin_amdgcn_mfma_f32_16x16x32_bf16(vf, pu.v, O[dt], 0, 0, 0);
        }
        __builtin_amdgcn_s_setprio(0);
    }

    // reduce l over quads (within wave): lv = sum over this wave's 32 keys
    float lv = l_acc;
    lv += __shfl_xor(lv, 16, 64);
    lv += __shfl_xor(lv, 32, 64);

    // pair-combine: waves 4-7 publish partials; waves 0-3 finalize
    __syncthreads();                         // all tile reads done; reuse LDS
    float* Oscr = reinterpret_cast<float*>(&sK[0][0]);      // 4*64*16 f32 = 16 KB
    float* lscr = reinterpret_cast<float*>(&sVt32[0][0]);   // 4*64 f32
    if (w4 == 1) {
        const int basei = wq * 1024 + lane * 16;
        #pragma unroll
        for (int dt = 0; dt < 4; dt++)
            #pragma unroll
            for (int j = 0; j < 4; j++)
                Oscr[basei + dt * 4 + j] = O[dt][j];
        lscr[wq * 64 + lane] = lv;
    }
    __syncthreads();
    if (w4 == 0) {
        const int basei = wq * 1024 + lane * 16;
        #pragma unroll
        for (int dt = 0; dt < 4; dt++)
            #pragma unroll
            for (int j = 0; j < 4; j++)
                O[dt][j] += Oscr[basei + dt * 4 + j];
        lv += lscr[wq * 64 + lane];
        const float inv = 1.0f / lv;
        const int qrow = qt * 64 + wq * 16 + l16;
        u16* orow = qkvb + bb + (size_t)qrow * QKV_N + h * DHEAD;
        #pragma unroll
        for (int dt = 0; dt < 4; dt++) {
            u32x2 pk;
            pk.x = cvt_pk_bf16(O[dt][0] * inv, O[dt][1] * inv);
            pk.y = cvt_pk_bf16(O[dt][2] * inv, O[dt][3] * inv);
            *reinterpret_cast<u32x2*>(&orow[dt * 16 + quad * 4]) = pk;
        }
    }
}

// ---------------------------------------------------------------------------
extern "C" void kernel_launch(void* const* d_in, const int* in_sizes, int n_in,
                              void* d_out, int out_size, void* d_ws, size_t ws_size,
                              hipStream_t stream)
{
    const float* x      = (const float*)d_in[0];
    const float* cosb   = (const float*)d_in[1];
    const float* sinb   = (const float*)d_in[2];
    const float* qkv_w  = (const float*)d_in[3];
    const float* qkv_b  = (const float*)d_in[4];
    const float* proj_w = (const float*)d_in[5];
    const float* proj_b = (const float*)d_in[6];
    const float* qn_w   = (const float*)d_in[7];
    const float* kn_w   = (const float*)d_in[8];
    float* out = (float*)d_out;

    char* ws = (char*)d_ws;
    u16* qkvb = (u16*)(ws);                    // 4096 x 2304 bf16 = 18,874,368 B
    u16* xb   = (u16*)(ws + 18874368);         // 4096 x 768  bf16 =  6,291,456 B
    u16* wT   = (u16*)(ws + 25165824);         // 2304 x 768  bf16 =  3,538,944 B
    u16* pwT  = (u16*)(ws + 28704768);         //  768 x 768  bf16 =  1,179,648 B

    // 0. fused prep: x->bf16, both weight transposes
    prep_kernel<<<PREP_CONV + PREP_TQ + PREP_TP, 256, 0, stream>>>(
        x, xb, qkv_w, wT, proj_w, pwT);

    // 1. QKV projection + fused RMSNorm/RoPE -> bf16 qkv buffer (dbuf)
    gemm_qkv_mfma_kernel<<<576, 256, 0, stream>>>(
        xb, CDIM, wT, qkv_b, cosb, sinb, qn_w, kn_w, qkvb, QKV_N, CDIM);

    // 2. Flash MFMA attention, 8-wave key-split + permlane P + K-DMA
    attn_mfma_kernel<<<dim3(SEQ / 64, HEADS, BATCH), 512, 0, stream>>>(qkvb);

    // 3. Output projection (bf16 MFMA 64x64 dbuf, fp32 out)
    gemm_proj_mfma_kernel<<<768, 256, 0, stream>>>(
        qkvb, QKV_N, pwT, proj_b, out, CDIM, CDIM);
}

// Round 11
// 169.470 us; speedup vs baseline: 1.0036x; 1.0036x over previous
//
#include <hip/hip_runtime.h>
#include <hip/hip_bf16.h>

// Problem constants
#define BATCH 2
#define SEQ   2048
#define CDIM  768
#define HEADS 12
#define DHEAD 64
#define QKV_N 2304   // 3*CDIM
#define ROWS  4096   // BATCH*SEQ

typedef unsigned short u16;
typedef unsigned int   u32;
typedef __attribute__((ext_vector_type(4))) float f32x4;
typedef __attribute__((ext_vector_type(8))) short bf16x8;
typedef __attribute__((ext_vector_type(2))) unsigned int u32x2;

// fp32 -> bf16 (RNE) bit pattern
__device__ __forceinline__ u16 f2b(float f) {
    union { float f; unsigned u; } v; v.f = f;
    unsigned r = v.u + 0x7FFF + ((v.u >> 16) & 1u);
    return (u16)(r >> 16);
}
// bf16 bits -> fp32
__device__ __forceinline__ float b2f(u16 u) {
    union { unsigned i; float f; } x;
    x.i = ((unsigned)u) << 16;
    return x.f;
}
// pack two fp32 -> one u32 of 2x bf16 (RNE), single VALU instruction.
__device__ __forceinline__ u32 cvt_pk_bf16(float lo, float hi) {
    u32 r;
    asm("v_cvt_pk_bf16_f32 %0, %1, %2" : "=v"(r) : "v"(lo), "v"(hi));
    return r;
}

// exp2: native v_exp_f32 when builtin available
#if __has_builtin(__builtin_amdgcn_exp2f)
#define EXP2(x) __builtin_amdgcn_exp2f(x)
#else
#define EXP2(x) __expf((x) * 0.69314718056f)
#endif

// async global->LDS 16B copy
__device__ __forceinline__ void load_lds16(const void* g, void* l) {
    __builtin_amdgcn_global_load_lds(
        (const __attribute__((address_space(1))) u32*)g,
        (__attribute__((address_space(3))) u32*)l, 16, 0, 0);
}

// ---------------------------------------------------------------------------
// Fused prep: x->bf16 (blocks [0,3072)), qkv_w transpose-convert
// (blocks [3072,4800)), proj_w transpose-convert (blocks [4800,5376)).
// V12: tconv vectorized — float4 loads (1/thread, full 128B/row coalescing)
// and packed u32 stores (2 bf16/store). Same values, same positions.
// ---------------------------------------------------------------------------
#define PREP_CONV 3072          // 4096*768/4 float4 / 256
#define PREP_TQ   1728          // (2304/32) x (768/32)
#define PREP_TP   576           // (768/32) x (768/32)

__device__ __forceinline__ void tconv_body(
    const float* __restrict__ in, u16* __restrict__ out, int R, int C,
    int bi, int bj)
{
    __shared__ float t[32][33];
    // load: 32x32 f32 tile, float4-vectorized (8 thr x 16B = 128B per row)
    const int lr = threadIdx.x >> 3;        // 0..31
    const int lc = (threadIdx.x & 7) * 4;   // 0,4,..,28
    const float4 v = *reinterpret_cast<const float4*>(
        &in[(size_t)(bi * 32 + lr) * C + bj * 32 + lc]);
    t[lr][lc] = v.x; t[lr][lc + 1] = v.y; t[lr][lc + 2] = v.z; t[lr][lc + 3] = v.w;
    __syncthreads();
    // store transposed: packed u32 (2 adjacent out-cols = 2 LDS rows).
    // bank audit: t[sc][r] stride 66 f32 -> bank (2k+r)%32, 2 lanes/bank (free).
    const int sr0 = threadIdx.x >> 4;       // 0..15
    const int sc  = (threadIdx.x & 15) * 2; // 0,2,..,30
    #pragma unroll
    for (int i = 0; i < 2; i++) {
        const int r = sr0 + i * 16;
        const u32 p = (u32)f2b(t[sc][r]) | ((u32)f2b(t[sc + 1][r]) << 16);
        *reinterpret_cast<u32*>(&out[(size_t)(bj * 32 + r) * R + bi * 32 + sc]) = p;
    }
}

__global__ __launch_bounds__(256) void prep_kernel(
    const float* __restrict__ x, u16* __restrict__ xb,
    const float* __restrict__ qkv_w, u16* __restrict__ wT,
    const float* __restrict__ proj_w, u16* __restrict__ pwT)
{
    const int bid = blockIdx.x;
    if (bid < PREP_CONV) {
        const int i = bid * 256 + threadIdx.x;
        const float4 v = reinterpret_cast<const float4*>(x)[i];
        ushort4 o;
        o.x = f2b(v.x); o.y = f2b(v.y); o.z = f2b(v.z); o.w = f2b(v.w);
        reinterpret_cast<ushort4*>(xb)[i] = o;
    } else if (bid < PREP_CONV + PREP_TQ) {
        const int t = bid - PREP_CONV;
        tconv_body(qkv_w, wT, CDIM, QKV_N, t / 72, t % 72);
    } else {
        const int t = bid - PREP_CONV - PREP_TQ;
        tconv_body(proj_w, pwT, CDIM, CDIM, t / 24, t % 24);
    }
}

// ---------------------------------------------------------------------------
// bf16 MFMA GEMM 128x128 BK32, DOUBLE-BUFFERED LDS (1 barrier/K-step),
// + FUSED RMSNorm + RoPE epilogue. q pre-scaled by Dh^-0.5 * log2(e).
// 1-D grid (576 blocks) with XCD-aware swizzle: 576%8==0, bijective remap.
// V6: RoPE-PAIR COLUMN PERMUTATION (partners in-register, packed u32 stores).
// ---------------------------------------------------------------------------
__device__ __forceinline__ int bperm(int row) {
    const int p = row & 63;
    const int j = p >> 4, l = p & 15;
    return (row & ~63) | ((j & 1) + 2 * l + 32 * (j >> 1));
}

__global__ __launch_bounds__(256) void gemm_qkv_mfma_kernel(
    const u16* __restrict__ A, int lda,
    const u16* __restrict__ BT,
    const float* __restrict__ bias,
    const float* __restrict__ cosb, const float* __restrict__ sinb,
    const float* __restrict__ qn, const float* __restrict__ kn,
    u16* __restrict__ C, int ldc, int K)
{
    __shared__ u16 sA[2][128 * 32];
    __shared__ u16 sB[2][128 * 32];
    const int tid = threadIdx.x;
    const int lane = tid & 63;
    const int wave = tid >> 6;
    const int wy = wave >> 1, wx = wave & 1;
    const int l16 = lane & 15, quad = lane >> 4;

    // XCD swizzle: consecutive ids round-robin XCDs; give each XCD a
    // contiguous chunk of tile space (72 tiles = 4 m-rows) for L2 locality.
    int id = blockIdx.x;
    id = (id & 7) * 72 + (id >> 3);        // 576/8 = 72
    const int m0 = (id / 18) * 128, n0 = (id % 18) * 128;

    // staging indices (2 granules each of A and B per thread)
    const int srow0 = tid >> 2,         sg0 = tid & 3;
    const int srow1 = (tid + 256) >> 2, sg1 = tid & 3;   // f = tid+256

    // permuted B source rows (RoPE-pair layout)
    const int brow0 = bperm(n0 + srow0);
    const int brow1 = bperm(n0 + srow1);

    f32x4 acc[4][4] = {};
    const int NK = K / 32;

    // prologue: stage k-step 0 into buffer 0
    load_lds16(A  + (size_t)(m0 + srow0) * lda + sg0 * 8, &sA[0][tid * 8]);
    load_lds16(BT + (size_t)brow0 * K          + sg0 * 8, &sB[0][tid * 8]);
    load_lds16(A  + (size_t)(m0 + srow1) * lda + sg1 * 8, &sA[0][(tid + 256) * 8]);
    load_lds16(BT + (size_t)brow1 * K          + sg1 * 8, &sB[0][(tid + 256) * 8]);

    for (int kt = 0; kt < NK; kt++) {
        const int cur = kt & 1;
        __syncthreads();   // DMA into buf[cur] complete; prior reads of buf[cur^1] done
        if (kt + 1 < NK) {
            const int nxt = cur ^ 1;
            const int k0 = (kt + 1) * 32;
            load_lds16(A  + (size_t)(m0 + srow0) * lda + k0 + sg0 * 8, &sA[nxt][tid * 8]);
            load_lds16(BT + (size_t)brow0 * K          + k0 + sg0 * 8, &sB[nxt][tid * 8]);
            load_lds16(A  + (size_t)(m0 + srow1) * lda + k0 + sg1 * 8, &sA[nxt][(tid + 256) * 8]);
            load_lds16(BT + (size_t)brow1 * K          + k0 + sg1 * 8, &sB[nxt][(tid + 256) * 8]);
        }

        bf16x8 af[4], bfr[4];
        #pragma unroll
        for (int i = 0; i < 4; i++) {
            af[i]  = *reinterpret_cast<const bf16x8*>(
                &sA[cur][(wy * 64 + i * 16 + l16) * 32 + quad * 8]);
            bfr[i] = *reinterpret_cast<const bf16x8*>(
                &sB[cur][(wx * 64 + i * 16 + l16) * 32 + quad * 8]);
        }
        #pragma unroll
        for (int i = 0; i < 4; i++)
            #pragma unroll
            for (int j = 0; j < 4; j++)
                acc[i][j] = __builtin_amdgcn_mfma_f32_16x16x32_bf16(
                    af[i], bfr[j], acc[i][j], 0, 0, 0);
    }

    // ---- fused epilogue (thread holds logical cols 2*l16,2*l16+1,32+2*l16,33+2*l16) ----
    const int cb = (n0 + wx * 64) >> 6;   // 64-col block, 0..35
    const int s  = cb / 12;               // 0=q, 1=k, 2=v
    const int colbase = n0 + wx * 64;
    // logical col offsets within head for j=0..3
    const int d0 = 2 * l16, d1 = 2 * l16 + 1, d2 = 2 * l16 + 32, d3 = 2 * l16 + 33;
    float bv[4];
    bv[0] = bias[colbase + d0]; bv[1] = bias[colbase + d1];
    bv[2] = bias[colbase + d2]; bv[3] = bias[colbase + d3];
    float wv[4];
    if (s < 2) {
        const float* wn = (s == 0) ? qn : kn;
        wv[0] = wn[d0]; wv[1] = wn[d1]; wv[2] = wn[d2]; wv[3] = wn[d3];
    }

    #pragma unroll
    for (int i = 0; i < 4; i++) {
        #pragma unroll
        for (int r = 0; r < 4; r++) {
            const int row = m0 + wy * 64 + i * 16 + quad * 4 + r;
            float v[4];
            #pragma unroll
            for (int j = 0; j < 4; j++) v[j] = acc[i][j][r] + bv[j];

            if (s < 2) {
                float sq = v[0]*v[0] + v[1]*v[1] + v[2]*v[2] + v[3]*v[3];
                #pragma unroll
                for (int off = 1; off < 16; off <<= 1)
                    sq += __shfl_xor(sq, off, 64);
                const float rms = rsqrtf(sq * (1.0f / 64.0f) + 1e-6f);
                const int n = row & (SEQ - 1);
                const float nv0 = v[0] * rms * wv[0];
                const float nv1 = v[1] * rms * wv[1];
                const float nv2 = v[2] * rms * wv[2];
                const float nv3 = v[3] * rms * wv[3];
                const float c0 = cosb[n * 32 + l16],      s0 = sinb[n * 32 + l16];
                const float c1 = cosb[n * 32 + 16 + l16], s1 = sinb[n * 32 + 16 + l16];
                v[0] = nv0 * c0 - nv1 * s0;
                v[1] = nv0 * s0 + nv1 * c0;
                v[2] = nv2 * c1 - nv3 * s1;
                v[3] = nv2 * s1 + nv3 * c1;
                if (s == 0) {
                    // fold Dh^-0.5 * log2(e) into q: scores land in exp2 domain
                    v[0] *= 0.18033688011112042f; v[1] *= 0.18033688011112042f;
                    v[2] *= 0.18033688011112042f; v[3] *= 0.18033688011112042f;
                }
            }
            u32* cw = reinterpret_cast<u32*>(&C[(size_t)row * ldc + colbase]);
            cw[l16]      = cvt_pk_bf16(v[0], v[1]);   // u16 cols 2*l16, 2*l16+1
            cw[16 + l16] = cvt_pk_bf16(v[2], v[3]);   // u16 cols 32+2*l16, 33+2*l16
        }
    }
}

// ---------------------------------------------------------------------------
// bf16 MFMA GEMM 64x64 BK32, double-buffered, fp32 output + bias.
// 1-D grid (768 blocks) with XCD-aware swizzle (768%8==0, bijective).
// ---------------------------------------------------------------------------
__global__ __launch_bounds__(256) void gemm_proj_mfma_kernel(
    const u16* __restrict__ A, int lda,
    const u16* __restrict__ BT,
    const float* __restrict__ bias,
    float* __restrict__ C, int ldc, int K)
{
    __shared__ u16 sA[2][64 * 32];
    __shared__ u16 sB[2][64 * 32];
    const int tid = threadIdx.x;
    const int lane = tid & 63;
    const int wave = tid >> 6;
    const int l16 = lane & 15, quad = lane >> 4;

    int id = blockIdx.x;
    id = (id & 7) * 96 + (id >> 3);        // 768/8 = 96
    const int m0 = (id / 12) * 64, n0 = (id % 12) * 64;

    const int srow = tid >> 2, sg = tid & 3;   // 256 granules per matrix

    f32x4 acc[4] = {};
    const int NK = K / 32;

    load_lds16(A  + (size_t)(m0 + srow) * lda + sg * 8, &sA[0][tid * 8]);
    load_lds16(BT + (size_t)(n0 + srow) * K   + sg * 8, &sB[0][tid * 8]);

    for (int kt = 0; kt < NK; kt++) {
        const int cur = kt & 1;
        __syncthreads();
        if (kt + 1 < NK) {
            const int nxt = cur ^ 1;
            const int k0 = (kt + 1) * 32;
            load_lds16(A  + (size_t)(m0 + srow) * lda + k0 + sg * 8, &sA[nxt][tid * 8]);
            load_lds16(BT + (size_t)(n0 + srow) * K   + k0 + sg * 8, &sB[nxt][tid * 8]);
        }

        const bf16x8 af = *reinterpret_cast<const bf16x8*>(
            &sA[cur][(wave * 16 + l16) * 32 + quad * 8]);
        bf16x8 bfr[4];
        #pragma unroll
        for (int j = 0; j < 4; j++)
            bfr[j] = *reinterpret_cast<const bf16x8*>(
                &sB[cur][(j * 16 + l16) * 32 + quad * 8]);
        #pragma unroll
        for (int j = 0; j < 4; j++)
            acc[j] = __builtin_amdgcn_mfma_f32_16x16x32_bf16(
                af, bfr[j], acc[j], 0, 0, 0);
    }

    float bv[4];
    #pragma unroll
    for (int j = 0; j < 4; j++) bv[j] = bias[n0 + j * 16 + l16];
    #pragma unroll
    for (int r = 0; r < 4; r++) {
        const int row = m0 + wave * 16 + quad * 4 + r;
        #pragma unroll
        for (int j = 0; j < 4; j++) {
            const int col = n0 + j * 16 + l16;
            C[(size_t)row * ldc + col] = acc[j][r] + bv[j];
        }
    }
}

// ---------------------------------------------------------------------------
// Flash MFMA attention V10 (REVERT of V11's K-DMA regression): 8-wave
// key-split (512 thr), permlane P exchange, K staged via regs + ds_write
// with granule-XOR swizzle, V pre-barrier reg-prefetch. Known-good 47.1 us.
// ---------------------------------------------------------------------------
__global__ __launch_bounds__(512) void attn_mfma_kernel(u16* __restrict__ qkvb)
{
    const int qt = blockIdx.x;   // q tile (64 rows)
    const int h  = blockIdx.y;
    const int b  = blockIdx.z;
    const int tid  = threadIdx.x;
    const int wave = tid >> 6;        // 0..7
    const int wq   = wave & 3;        // q-row group
    const int w4   = wave >> 2;       // key-half (0: keys 0-31, 1: keys 32-63)
    const int lane = tid & 63;
    const int l16  = lane & 15;
    const int quad = lane >> 4;

    const size_t bb = (size_t)b * SEQ * QKV_N;
    const u16* Kg = qkvb + bb + CDIM     + h * DHEAD;
    const u16* Vg = qkvb + bb + 2 * CDIM + h * DHEAD;
    const u16* Qg = qkvb + bb + (size_t)(qt * 64) * QKV_N + h * DHEAD;

    __shared__ u16 sK[2][64 * 64];   // granule-XOR swizzled, no pad
    __shared__ u32 sVt32[2][64 * 32];

    // staging: 512 threads stage one K row each; V rows in pairs with d-split
    const int kq = tid >> 3;          // K row 0..63
    const int g  = tid & 7;           // 16B granule (d = g*8..g*8+7)
    const int kp = (tid >> 3) & 31;   // V key pair: rows 2kp, 2kp+1
    const int e0 = (tid >> 8) * 4;    // d-subrange within granule: 0..3 or 4..7

    bf16x8 qf[2];
    {
        const u16* qrow = Qg + (size_t)(wq * 16 + l16) * QKV_N;
        qf[0] = *reinterpret_cast<const bf16x8*>(qrow + quad * 8);
        qf[1] = *reinterpret_cast<const bf16x8*>(qrow + 32 + quad * 8);
    }

    f32x4 O[4] = {};        // O^T partial (this wave's key-half): rows d, cols q
    float l_acc = 0.f;

    bf16x8 kreg;
    u32x2 vreg0, vreg1;
    kreg  = *reinterpret_cast<const bf16x8*>(Kg + (size_t)kq * QKV_N + g * 8);
    vreg0 = *reinterpret_cast<const u32x2*>(Vg + (size_t)(2 * kp)     * QKV_N + g * 8 + e0);
    vreg1 = *reinterpret_cast<const u32x2*>(Vg + (size_t)(2 * kp + 1) * QKV_N + g * 8 + e0);

    const int kg_swz = (g ^ (kq & 7)) * 8;
    const int ks = l16 & 7;           // read-side row swizzle key

    const int NT = SEQ / 64;
    for (int t = 0; t < NT; t++) {
        const int cur = t & 1;
        // stage tile t from prefetched regs
        *reinterpret_cast<bf16x8*>(&sK[cur][kq * 64 + kg_swz]) = kreg;
        const int pwv = kp ^ (4 * g) ^ ((g & 1) << 4);
        {
            const u32* v0w = reinterpret_cast<const u32*>(&vreg0);
            const u32* v1w = reinterpret_cast<const u32*>(&vreg1);
            #pragma unroll
            for (int el = 0; el < 4; el++) {
                const u32 pack = __builtin_amdgcn_perm(
                    v1w[el >> 1], v0w[el >> 1],
                    (el & 1) ? 0x07060302u : 0x05040100u);
                sVt32[cur][(g * 8 + e0 + el) * 32 + pwv] = pack;
            }
        }
        if (t + 1 < NT) {
            const size_t base = (size_t)(t + 1) * 64;
            kreg  = *reinterpret_cast<const bf16x8*>(Kg + (base + kq) * QKV_N + g * 8);
            vreg0 = *reinterpret_cast<const u32x2*>(Vg + (base + 2 * kp)     * QKV_N + g * 8 + e0);
            vreg1 = *reinterpret_cast<const u32x2*>(Vg + (base + 2 * kp + 1) * QKV_N + g * 8 + e0);
        }
        __syncthreads();

        // S^T for this wave's key-half: kt = w4*2 + i
        f32x4 s[2];
        __builtin_amdgcn_s_setprio(1);
        #pragma unroll
        for (int i = 0; i < 2; i++) {
            const int krow = (w4 * 2 + i) * 16 + l16;
            bf16x8 kf0 = *reinterpret_cast<const bf16x8*>(
                &sK[cur][krow * 64 + ((quad ^ ks) * 8)]);
            bf16x8 kf1 = *reinterpret_cast<const bf16x8*>(
                &sK[cur][krow * 64 + (((quad + 4) ^ ks) * 8)]);
            f32x4 a = {};
            a = __builtin_amdgcn_mfma_f32_16x16x32_bf16(kf0, qf[0], a, 0, 0, 0);
            a = __builtin_amdgcn_mfma_f32_16x16x32_bf16(kf1, qf[1], a, 0, 0, 0);
            s[i] = a;
        }
        __builtin_amdgcn_s_setprio(0);

        // P = exp2(S); l_acc in the same order as before (i=0 then i=1)
        u32 ax, ay, bx, by;
        {
            float p0 = EXP2(s[0][0]);
            float p1 = EXP2(s[0][1]);
            float p2 = EXP2(s[0][2]);
            float p3 = EXP2(s[0][3]);
            l_acc += p0; l_acc += p1; l_acc += p2; l_acc += p3;
            ax = cvt_pk_bf16(p0, p1);
            ay = cvt_pk_bf16(p2, p3);
        }
        {
            float p0 = EXP2(s[1][0]);
            float p1 = EXP2(s[1][1]);
            float p2 = EXP2(s[1][2]);
            float p3 = EXP2(s[1][3]);
            l_acc += p0; l_acc += p1; l_acc += p2; l_acc += p3;
            bx = cvt_pk_bf16(p0, p1);
            by = cvt_pk_bf16(p2, p3);
        }
        // in-register quad exchange (replaces sP2 write+read):
        asm("v_permlane32_swap_b32 %0, %1" : "+v"(ax), "+v"(bx));
        asm("v_permlane32_swap_b32 %0, %1" : "+v"(ay), "+v"(by));
        asm("v_permlane16_swap_b32 %0, %1" : "+v"(ax), "+v"(bx));
        asm("v_permlane16_swap_b32 %0, %1" : "+v"(ay), "+v"(by));

        union { struct { u32x2 lo, hi; } s2; bf16x8 v; } pu;
        pu.s2.lo.x = ax; pu.s2.lo.y = ay;   // keys w4*32+quad*8 .. +3
        pu.s2.hi.x = bx; pu.s2.hi.y = by;   // keys w4*32+quad*8+4 .. +7

        // O^T += V^T P^T over this wave's 32 keys (1 MFMA per dt)
        __builtin_amdgcn_s_setprio(1);
        #pragma unroll
        for (int dt = 0; dt < 4; dt++) {
            const int row = dt * 16 + l16;
            const int hr  = (row >> 3) & 7;
            const int sw  = (4 * hr) ^ ((hr & 1) << 4);
            bf16x8 vf = *reinterpret_cast<const bf16x8*>(
                &sVt32[cur][row * 32 + ((w4 * 16 + quad * 4) ^ sw)]);
            O[dt] = __builtin_amdgcn_mfma_f32_16x16x32_bf16(vf, pu.v, O[dt], 0, 0, 0);
        }
        __builtin_amdgcn_s_setprio(0);
    }

    // reduce l over quads (within wave): lv = sum over this wave's 32 keys
    float lv = l_acc;
    lv += __shfl_xor(lv, 16, 64);
    lv += __shfl_xor(lv, 32, 64);

    // pair-combine: waves 4-7 publish partials; waves 0-3 finalize
    __syncthreads();                         // all tile reads done; reuse LDS
    float* Oscr = reinterpret_cast<float*>(&sK[0][0]);      // 4*64*16 f32 = 16 KB
    float* lscr = reinterpret_cast<float*>(&sVt32[0][0]);   // 4*64 f32
    if (w4 == 1) {
        const int basei = wq * 1024 + lane * 16;
        #pragma unroll
        for (int dt = 0; dt < 4; dt++)
            #pragma unroll
            for (int j = 0; j < 4; j++)
                Oscr[basei + dt * 4 + j] = O[dt][j];
        lscr[wq * 64 + lane] = lv;
    }
    __syncthreads();
    if (w4 == 0) {
        const int basei = wq * 1024 + lane * 16;
        #pragma unroll
        for (int dt = 0; dt < 4; dt++)
            #pragma unroll
            for (int j = 0; j < 4; j++)
                O[dt][j] += Oscr[basei + dt * 4 + j];
        lv += lscr[wq * 64 + lane];
        const float inv = 1.0f / lv;
        const int qrow = qt * 64 + wq * 16 + l16;
        u16* orow = qkvb + bb + (size_t)qrow * QKV_N + h * DHEAD;
        #pragma unroll
        for (int dt = 0; dt < 4; dt++) {
            u32x2 pk;
            pk.x = cvt_pk_bf16(O[dt][0] * inv, O[dt][1] * inv);
            pk.y = cvt_pk_bf16(O[dt][2] * inv, O[dt][3] * inv);
            *reinterpret_cast<u32x2*>(&orow[dt * 16 + quad * 4]) = pk;
        }
    }
}

// ---------------------------------------------------------------------------
extern "C" void kernel_launch(void* const* d_in, const int* in_sizes, int n_in,
                              void* d_out, int out_size, void* d_ws, size_t ws_size,
                              hipStream_t stream)
{
    const float* x      = (const float*)d_in[0];
    const float* cosb   = (const float*)d_in[1];
    const float* sinb   = (const float*)d_in[2];
    const float* qkv_w  = (const float*)d_in[3];
    const float* qkv_b  = (const float*)d_in[4];
    const float* proj_w = (const float*)d_in[5];
    const float* proj_b = (const float*)d_in[6];
    const float* qn_w   = (const float*)d_in[7];
    const float* kn_w   = (const float*)d_in[8];
    float* out = (float*)d_out;

    char* ws = (char*)d_ws;
    u16* qkvb = (u16*)(ws);                    // 4096 x 2304 bf16 = 18,874,368 B
    u16* xb   = (u16*)(ws + 18874368);         // 4096 x 768  bf16 =  6,291,456 B
    u16* wT   = (u16*)(ws + 25165824);         // 2304 x 768  bf16 =  3,538,944 B
    u16* pwT  = (u16*)(ws + 28704768);         //  768 x 768  bf16 =  1,179,648 B

    // 0. fused prep: x->bf16, both weight transposes
    prep_kernel<<<PREP_CONV + PREP_TQ + PREP_TP, 256, 0, stream>>>(
        x, xb, qkv_w, wT, proj_w, pwT);

    // 1. QKV projection + fused RMSNorm/RoPE -> bf16 qkv buffer (dbuf)
    gemm_qkv_mfma_kernel<<<576, 256, 0, stream>>>(
        xb, CDIM, wT, qkv_b, cosb, sinb, qn_w, kn_w, qkvb, QKV_N, CDIM);

    // 2. Flash MFMA attention, 8-wave key-split + permlane P (out -> q slot)
    attn_mfma_kernel<<<dim3(SEQ / 64, HEADS, BATCH), 512, 0, stream>>>(qkvb);

    // 3. Output projection (bf16 MFMA 64x64 dbuf, fp32 out)
    gemm_proj_mfma_kernel<<<768, 256, 0, stream>>>(
        qkvb, QKV_N, pwT, proj_b, out, CDIM, CDIM);
}

// Round 12
// 166.211 us; speedup vs baseline: 1.0233x; 1.0196x over previous
//
#include <hip/hip_runtime.h>
#include <hip/hip_bf16.h>

// Problem constants
#define BATCH 2
#define SEQ   2048
#define CDIM  768
#define HEADS 12
#define DHEAD 64
#define QKV_N 2304   // 3*CDIM
#define ROWS  4096   // BATCH*SEQ

typedef unsigned short u16;
typedef unsigned int   u32;
typedef __attribute__((ext_vector_type(4))) float f32x4;
typedef __attribute__((ext_vector_type(8))) short bf16x8;
typedef __attribute__((ext_vector_type(2))) unsigned int u32x2;

// fp32 -> bf16 (RNE) bit pattern
__device__ __forceinline__ u16 f2b(float f) {
    union { float f; unsigned u; } v; v.f = f;
    unsigned r = v.u + 0x7FFF + ((v.u >> 16) & 1u);
    return (u16)(r >> 16);
}
// bf16 bits -> fp32
__device__ __forceinline__ float b2f(u16 u) {
    union { unsigned i; float f; } x;
    x.i = ((unsigned)u) << 16;
    return x.f;
}
// pack two fp32 -> one u32 of 2x bf16 (RNE), single VALU instruction.
__device__ __forceinline__ u32 cvt_pk_bf16(float lo, float hi) {
    u32 r;
    asm("v_cvt_pk_bf16_f32 %0, %1, %2" : "=v"(r) : "v"(lo), "v"(hi));
    return r;
}

// exp2: native v_exp_f32 when builtin available
#if __has_builtin(__builtin_amdgcn_exp2f)
#define EXP2(x) __builtin_amdgcn_exp2f(x)
#else
#define EXP2(x) __expf((x) * 0.69314718056f)
#endif

// async global->LDS 16B copy
__device__ __forceinline__ void load_lds16(const void* g, void* l) {
    __builtin_amdgcn_global_load_lds(
        (const __attribute__((address_space(1))) u32*)g,
        (__attribute__((address_space(3))) u32*)l, 16, 0, 0);
}

// ---------------------------------------------------------------------------
// Fused prep: x->bf16 (blocks [0,3072)), qkv_w transpose-convert
// (blocks [3072,4800)), proj_w transpose-convert (blocks [4800,5376)).
// V12: tconv vectorized — float4 loads + packed u32 stores.
// ---------------------------------------------------------------------------
#define PREP_CONV 3072          // 4096*768/4 float4 / 256
#define PREP_TQ   1728          // (2304/32) x (768/32)
#define PREP_TP   576           // (768/32) x (768/32)

__device__ __forceinline__ void tconv_body(
    const float* __restrict__ in, u16* __restrict__ out, int R, int C,
    int bi, int bj)
{
    __shared__ float t[32][33];
    const int lr = threadIdx.x >> 3;        // 0..31
    const int lc = (threadIdx.x & 7) * 4;   // 0,4,..,28
    const float4 v = *reinterpret_cast<const float4*>(
        &in[(size_t)(bi * 32 + lr) * C + bj * 32 + lc]);
    t[lr][lc] = v.x; t[lr][lc + 1] = v.y; t[lr][lc + 2] = v.z; t[lr][lc + 3] = v.w;
    __syncthreads();
    const int sr0 = threadIdx.x >> 4;       // 0..15
    const int sc  = (threadIdx.x & 15) * 2; // 0,2,..,30
    #pragma unroll
    for (int i = 0; i < 2; i++) {
        const int r = sr0 + i * 16;
        const u32 p = (u32)f2b(t[sc][r]) | ((u32)f2b(t[sc + 1][r]) << 16);
        *reinterpret_cast<u32*>(&out[(size_t)(bj * 32 + r) * R + bi * 32 + sc]) = p;
    }
}

__global__ __launch_bounds__(256) void prep_kernel(
    const float* __restrict__ x, u16* __restrict__ xb,
    const float* __restrict__ qkv_w, u16* __restrict__ wT,
    const float* __restrict__ proj_w, u16* __restrict__ pwT)
{
    const int bid = blockIdx.x;
    if (bid < PREP_CONV) {
        const int i = bid * 256 + threadIdx.x;
        const float4 v = reinterpret_cast<const float4*>(x)[i];
        ushort4 o;
        o.x = f2b(v.x); o.y = f2b(v.y); o.z = f2b(v.z); o.w = f2b(v.w);
        reinterpret_cast<ushort4*>(xb)[i] = o;
    } else if (bid < PREP_CONV + PREP_TQ) {
        const int t = bid - PREP_CONV;
        tconv_body(qkv_w, wT, CDIM, QKV_N, t / 72, t % 72);
    } else {
        const int t = bid - PREP_CONV - PREP_TQ;
        tconv_body(proj_w, pwT, CDIM, CDIM, t / 24, t % 24);
    }
}

// ---------------------------------------------------------------------------
// bf16 MFMA GEMM 128x128 BK32, DOUBLE-BUFFERED LDS (1 barrier/K-step),
// + FUSED RMSNorm + RoPE epilogue. q pre-scaled by Dh^-0.5 * log2(e).
// 1-D grid (576 blocks) with XCD-aware swizzle: 576%8==0, bijective remap.
// V6: RoPE-PAIR COLUMN PERMUTATION (partners in-register, packed u32 stores).
// ---------------------------------------------------------------------------
__device__ __forceinline__ int bperm(int row) {
    const int p = row & 63;
    const int j = p >> 4, l = p & 15;
    return (row & ~63) | ((j & 1) + 2 * l + 32 * (j >> 1));
}

__global__ __launch_bounds__(256) void gemm_qkv_mfma_kernel(
    const u16* __restrict__ A, int lda,
    const u16* __restrict__ BT,
    const float* __restrict__ bias,
    const float* __restrict__ cosb, const float* __restrict__ sinb,
    const float* __restrict__ qn, const float* __restrict__ kn,
    u16* __restrict__ C, int ldc, int K)
{
    __shared__ u16 sA[2][128 * 32];
    __shared__ u16 sB[2][128 * 32];
    const int tid = threadIdx.x;
    const int lane = tid & 63;
    const int wave = tid >> 6;
    const int wy = wave >> 1, wx = wave & 1;
    const int l16 = lane & 15, quad = lane >> 4;

    // XCD swizzle: consecutive ids round-robin XCDs; give each XCD a
    // contiguous chunk of tile space (72 tiles = 4 m-rows) for L2 locality.
    int id = blockIdx.x;
    id = (id & 7) * 72 + (id >> 3);        // 576/8 = 72
    const int m0 = (id / 18) * 128, n0 = (id % 18) * 128;

    // staging indices (2 granules each of A and B per thread)
    const int srow0 = tid >> 2,         sg0 = tid & 3;
    const int srow1 = (tid + 256) >> 2, sg1 = tid & 3;   // f = tid+256

    // permuted B source rows (RoPE-pair layout)
    const int brow0 = bperm(n0 + srow0);
    const int brow1 = bperm(n0 + srow1);

    f32x4 acc[4][4] = {};
    const int NK = K / 32;

    // prologue: stage k-step 0 into buffer 0
    load_lds16(A  + (size_t)(m0 + srow0) * lda + sg0 * 8, &sA[0][tid * 8]);
    load_lds16(BT + (size_t)brow0 * K          + sg0 * 8, &sB[0][tid * 8]);
    load_lds16(A  + (size_t)(m0 + srow1) * lda + sg1 * 8, &sA[0][(tid + 256) * 8]);
    load_lds16(BT + (size_t)brow1 * K          + sg1 * 8, &sB[0][(tid + 256) * 8]);

    for (int kt = 0; kt < NK; kt++) {
        const int cur = kt & 1;
        __syncthreads();   // DMA into buf[cur] complete; prior reads of buf[cur^1] done
        if (kt + 1 < NK) {
            const int nxt = cur ^ 1;
            const int k0 = (kt + 1) * 32;
            load_lds16(A  + (size_t)(m0 + srow0) * lda + k0 + sg0 * 8, &sA[nxt][tid * 8]);
            load_lds16(BT + (size_t)brow0 * K          + k0 + sg0 * 8, &sB[nxt][tid * 8]);
            load_lds16(A  + (size_t)(m0 + srow1) * lda + k0 + sg1 * 8, &sA[nxt][(tid + 256) * 8]);
            load_lds16(BT + (size_t)brow1 * K          + k0 + sg1 * 8, &sB[nxt][(tid + 256) * 8]);
        }

        bf16x8 af[4], bfr[4];
        #pragma unroll
        for (int i = 0; i < 4; i++) {
            af[i]  = *reinterpret_cast<const bf16x8*>(
                &sA[cur][(wy * 64 + i * 16 + l16) * 32 + quad * 8]);
            bfr[i] = *reinterpret_cast<const bf16x8*>(
                &sB[cur][(wx * 64 + i * 16 + l16) * 32 + quad * 8]);
        }
        #pragma unroll
        for (int i = 0; i < 4; i++)
            #pragma unroll
            for (int j = 0; j < 4; j++)
                acc[i][j] = __builtin_amdgcn_mfma_f32_16x16x32_bf16(
                    af[i], bfr[j], acc[i][j], 0, 0, 0);
    }

    // ---- fused epilogue (thread holds logical cols 2*l16,2*l16+1,32+2*l16,33+2*l16) ----
    const int cb = (n0 + wx * 64) >> 6;   // 64-col block, 0..35
    const int s  = cb / 12;               // 0=q, 1=k, 2=v
    const int colbase = n0 + wx * 64;
    // logical col offsets within head for j=0..3
    const int d0 = 2 * l16, d1 = 2 * l16 + 1, d2 = 2 * l16 + 32, d3 = 2 * l16 + 33;
    float bv[4];
    bv[0] = bias[colbase + d0]; bv[1] = bias[colbase + d1];
    bv[2] = bias[colbase + d2]; bv[3] = bias[colbase + d3];
    float wv[4];
    if (s < 2) {
        const float* wn = (s == 0) ? qn : kn;
        wv[0] = wn[d0]; wv[1] = wn[d1]; wv[2] = wn[d2]; wv[3] = wn[d3];
    }

    #pragma unroll
    for (int i = 0; i < 4; i++) {
        #pragma unroll
        for (int r = 0; r < 4; r++) {
            const int row = m0 + wy * 64 + i * 16 + quad * 4 + r;
            float v[4];
            #pragma unroll
            for (int j = 0; j < 4; j++) v[j] = acc[i][j][r] + bv[j];

            if (s < 2) {
                float sq = v[0]*v[0] + v[1]*v[1] + v[2]*v[2] + v[3]*v[3];
                #pragma unroll
                for (int off = 1; off < 16; off <<= 1)
                    sq += __shfl_xor(sq, off, 64);
                const float rms = rsqrtf(sq * (1.0f / 64.0f) + 1e-6f);
                const int n = row & (SEQ - 1);
                const float nv0 = v[0] * rms * wv[0];
                const float nv1 = v[1] * rms * wv[1];
                const float nv2 = v[2] * rms * wv[2];
                const float nv3 = v[3] * rms * wv[3];
                const float c0 = cosb[n * 32 + l16],      s0 = sinb[n * 32 + l16];
                const float c1 = cosb[n * 32 + 16 + l16], s1 = sinb[n * 32 + 16 + l16];
                v[0] = nv0 * c0 - nv1 * s0;
                v[1] = nv0 * s0 + nv1 * c0;
                v[2] = nv2 * c1 - nv3 * s1;
                v[3] = nv2 * s1 + nv3 * c1;
                if (s == 0) {
                    // fold Dh^-0.5 * log2(e) into q: scores land in exp2 domain
                    v[0] *= 0.18033688011112042f; v[1] *= 0.18033688011112042f;
                    v[2] *= 0.18033688011112042f; v[3] *= 0.18033688011112042f;
                }
            }
            u32* cw = reinterpret_cast<u32*>(&C[(size_t)row * ldc + colbase]);
            cw[l16]      = cvt_pk_bf16(v[0], v[1]);   // u16 cols 2*l16, 2*l16+1
            cw[16 + l16] = cvt_pk_bf16(v[2], v[3]);   // u16 cols 32+2*l16, 33+2*l16
        }
    }
}

// ---------------------------------------------------------------------------
// bf16 MFMA GEMM 64x64, V13: BK=64 (36 K-steps, was 72) — halves barrier
// count, 8 MFMA/wave/phase. 128B row stride would be a 2x bank conflict on
// ds_read_b128 (bank = f(granule) only), so granule-XOR swizzle
// slot = g ^ (row&7), applied via PRE-SWIZZLED DMA SOURCE (linear LDS dest,
// m173 pattern) and XOR'd read addresses -> 8 words/bank (b128 floor).
// Accumulation order per acc[j] unchanged (ascending K slices) -> bitwise
// identical. LDS 32 KB -> still 3 blocks/CU (grid-capped).
// ---------------------------------------------------------------------------
__global__ __launch_bounds__(256) void gemm_proj_mfma_kernel(
    const u16* __restrict__ A, int lda,
    const u16* __restrict__ BT,
    const float* __restrict__ bias,
    float* __restrict__ C, int ldc, int K)
{
    __shared__ u16 sA[2][64 * 64];
    __shared__ u16 sB[2][64 * 64];
    const int tid = threadIdx.x;
    const int lane = tid & 63;
    const int wave = tid >> 6;
    const int l16 = lane & 15, quad = lane >> 4;

    int id = blockIdx.x;
    id = (id & 7) * 96 + (id >> 3);        // 768/8 = 96
    const int m0 = (id / 12) * 64, n0 = (id % 12) * 64;

    // staging: row = tid>>3 (0..31; +32 for second call), dest slot = tid&7,
    // source granule = slot ^ (row&7)  ((row+32)&7 == row&7)
    const int srow = tid >> 3;
    const int sgs  = (tid & 7) ^ (srow & 7);

    f32x4 acc[4] = {};
    const int NK2 = K / 64;   // 36

    load_lds16(A  + (size_t)(m0 + srow) * lda      + sgs * 8, &sA[0][tid * 8]);
    load_lds16(A  + (size_t)(m0 + srow + 32) * lda + sgs * 8, &sA[0][(tid + 256) * 8]);
    load_lds16(BT + (size_t)(n0 + srow) * K        + sgs * 8, &sB[0][tid * 8]);
    load_lds16(BT + (size_t)(n0 + srow + 32) * K   + sgs * 8, &sB[0][(tid + 256) * 8]);

    for (int kt = 0; kt < NK2; kt++) {
        const int cur = kt & 1;
        __syncthreads();
        if (kt + 1 < NK2) {
            const int nxt = cur ^ 1;
            const int k0 = (kt + 1) * 64;
            load_lds16(A  + (size_t)(m0 + srow) * lda      + k0 + sgs * 8, &sA[nxt][tid * 8]);
            load_lds16(A  + (size_t)(m0 + srow + 32) * lda + k0 + sgs * 8, &sA[nxt][(tid + 256) * 8]);
            load_lds16(BT + (size_t)(n0 + srow) * K        + k0 + sgs * 8, &sB[nxt][tid * 8]);
            load_lds16(BT + (size_t)(n0 + srow + 32) * K   + k0 + sgs * 8, &sB[nxt][(tid + 256) * 8]);
        }

        const int rA = wave * 16 + l16;
        #pragma unroll
        for (int h = 0; h < 2; h++) {
            const bf16x8 af = *reinterpret_cast<const bf16x8*>(
                &sA[cur][rA * 64 + (((h * 4 + quad) ^ (rA & 7)) * 8)]);
            #pragma unroll
            for (int j = 0; j < 4; j++) {
                const int rB = j * 16 + l16;
                const bf16x8 bfr = *reinterpret_cast<const bf16x8*>(
                    &sB[cur][rB * 64 + (((h * 4 + quad) ^ (rB & 7)) * 8)]);
                acc[j] = __builtin_amdgcn_mfma_f32_16x16x32_bf16(
                    af, bfr, acc[j], 0, 0, 0);
            }
        }
    }

    float bv[4];
    #pragma unroll
    for (int j = 0; j < 4; j++) bv[j] = bias[n0 + j * 16 + l16];
    #pragma unroll
    for (int r = 0; r < 4; r++) {
        const int row = m0 + wave * 16 + quad * 4 + r;
        #pragma unroll
        for (int j = 0; j < 4; j++) {
            const int col = n0 + j * 16 + l16;
            C[(size_t)row * ldc + col] = acc[j][r] + bv[j];
        }
    }
}

// ---------------------------------------------------------------------------
// Flash MFMA attention V10 (known-good): 8-wave key-split (512 thr),
// permlane P exchange, K staged via regs + ds_write with granule-XOR
// swizzle, V pre-barrier reg-prefetch.
// ---------------------------------------------------------------------------
__global__ __launch_bounds__(512) void attn_mfma_kernel(u16* __restrict__ qkvb)
{
    const int qt = blockIdx.x;   // q tile (64 rows)
    const int h  = blockIdx.y;
    const int b  = blockIdx.z;
    const int tid  = threadIdx.x;
    const int wave = tid >> 6;        // 0..7
    const int wq   = wave & 3;        // q-row group
    const int w4   = wave >> 2;       // key-half (0: keys 0-31, 1: keys 32-63)
    const int lane = tid & 63;
    const int l16  = lane & 15;
    const int quad = lane >> 4;

    const size_t bb = (size_t)b * SEQ * QKV_N;
    const u16* Kg = qkvb + bb + CDIM     + h * DHEAD;
    const u16* Vg = qkvb + bb + 2 * CDIM + h * DHEAD;
    const u16* Qg = qkvb + bb + (size_t)(qt * 64) * QKV_N + h * DHEAD;

    __shared__ u16 sK[2][64 * 64];   // granule-XOR swizzled, no pad
    __shared__ u32 sVt32[2][64 * 32];

    // staging: 512 threads stage one K row each; V rows in pairs with d-split
    const int kq = tid >> 3;          // K row 0..63
    const int g  = tid & 7;           // 16B granule (d = g*8..g*8+7)
    const int kp = (tid >> 3) & 31;   // V key pair: rows 2kp, 2kp+1
    const int e0 = (tid >> 8) * 4;    // d-subrange within granule: 0..3 or 4..7

    bf16x8 qf[2];
    {
        const u16* qrow = Qg + (size_t)(wq * 16 + l16) * QKV_N;
        qf[0] = *reinterpret_cast<const bf16x8*>(qrow + quad * 8);
        qf[1] = *reinterpret_cast<const bf16x8*>(qrow + 32 + quad * 8);
    }

    f32x4 O[4] = {};        // O^T partial (this wave's key-half): rows d, cols q
    float l_acc = 0.f;

    bf16x8 kreg;
    u32x2 vreg0, vreg1;
    kreg  = *reinterpret_cast<const bf16x8*>(Kg + (size_t)kq * QKV_N + g * 8);
    vreg0 = *reinterpret_cast<const u32x2*>(Vg + (size_t)(2 * kp)     * QKV_N + g * 8 + e0);
    vreg1 = *reinterpret_cast<const u32x2*>(Vg + (size_t)(2 * kp + 1) * QKV_N + g * 8 + e0);

    const int kg_swz = (g ^ (kq & 7)) * 8;
    const int ks = l16 & 7;           // read-side row swizzle key

    const int NT = SEQ / 64;
    for (int t = 0; t < NT; t++) {
        const int cur = t & 1;
        // stage tile t from prefetched regs
        *reinterpret_cast<bf16x8*>(&sK[cur][kq * 64 + kg_swz]) = kreg;
        const int pwv = kp ^ (4 * g) ^ ((g & 1) << 4);
        {
            const u32* v0w = reinterpret_cast<const u32*>(&vreg0);
            const u32* v1w = reinterpret_cast<const u32*>(&vreg1);
            #pragma unroll
            for (int el = 0; el < 4; el++) {
                const u32 pack = __builtin_amdgcn_perm(
                    v1w[el >> 1], v0w[el >> 1],
                    (el & 1) ? 0x07060302u : 0x05040100u);
                sVt32[cur][(g * 8 + e0 + el) * 32 + pwv] = pack;
            }
        }
        if (t + 1 < NT) {
            const size_t base = (size_t)(t + 1) * 64;
            kreg  = *reinterpret_cast<const bf16x8*>(Kg + (base + kq) * QKV_N + g * 8);
            vreg0 = *reinterpret_cast<const u32x2*>(Vg + (base + 2 * kp)     * QKV_N + g * 8 + e0);
            vreg1 = *reinterpret_cast<const u32x2*>(Vg + (base + 2 * kp + 1) * QKV_N + g * 8 + e0);
        }
        __syncthreads();

        // S^T for this wave's key-half: kt = w4*2 + i
        f32x4 s[2];
        __builtin_amdgcn_s_setprio(1);
        #pragma unroll
        for (int i = 0; i < 2; i++) {
            const int krow = (w4 * 2 + i) * 16 + l16;
            bf16x8 kf0 = *reinterpret_cast<const bf16x8*>(
                &sK[cur][krow * 64 + ((quad ^ ks) * 8)]);
            bf16x8 kf1 = *reinterpret_cast<const bf16x8*>(
                &sK[cur][krow * 64 + (((quad + 4) ^ ks) * 8)]);
            f32x4 a = {};
            a = __builtin_amdgcn_mfma_f32_16x16x32_bf16(kf0, qf[0], a, 0, 0, 0);
            a = __builtin_amdgcn_mfma_f32_16x16x32_bf16(kf1, qf[1], a, 0, 0, 0);
            s[i] = a;
        }
        __builtin_amdgcn_s_setprio(0);

        // P = exp2(S); l_acc in the same order as before (i=0 then i=1)
        u32 ax, ay, bx, by;
        {
            float p0 = EXP2(s[0][0]);
            float p1 = EXP2(s[0][1]);
            float p2 = EXP2(s[0][2]);
            float p3 = EXP2(s[0][3]);
            l_acc += p0; l_acc += p1; l_acc += p2; l_acc += p3;
            ax = cvt_pk_bf16(p0, p1);
            ay = cvt_pk_bf16(p2, p3);
        }
        {
            float p0 = EXP2(s[1][0]);
            float p1 = EXP2(s[1][1]);
            float p2 = EXP2(s[1][2]);
            float p3 = EXP2(s[1][3]);
            l_acc += p0; l_acc += p1; l_acc += p2; l_acc += p3;
            bx = cvt_pk_bf16(p0, p1);
            by = cvt_pk_bf16(p2, p3);
        }
        // in-register quad exchange (replaces sP2 write+read):
        asm("v_permlane32_swap_b32 %0, %1" : "+v"(ax), "+v"(bx));
        asm("v_permlane32_swap_b32 %0, %1" : "+v"(ay), "+v"(by));
        asm("v_permlane16_swap_b32 %0, %1" : "+v"(ax), "+v"(bx));
        asm("v_permlane16_swap_b32 %0, %1" : "+v"(ay), "+v"(by));

        union { struct { u32x2 lo, hi; } s2; bf16x8 v; } pu;
        pu.s2.lo.x = ax; pu.s2.lo.y = ay;   // keys w4*32+quad*8 .. +3
        pu.s2.hi.x = bx; pu.s2.hi.y = by;   // keys w4*32+quad*8+4 .. +7

        // O^T += V^T P^T over this wave's 32 keys (1 MFMA per dt)
        __builtin_amdgcn_s_setprio(1);
        #pragma unroll
        for (int dt = 0; dt < 4; dt++) {
            const int row = dt * 16 + l16;
            const int hr  = (row >> 3) & 7;
            const int sw  = (4 * hr) ^ ((hr & 1) << 4);
            bf16x8 vf = *reinterpret_cast<const bf16x8*>(
                &sVt32[cur][row * 32 + ((w4 * 16 + quad * 4) ^ sw)]);
            O[dt] = __builtin_amdgcn_mfma_f32_16x16x32_bf16(vf, pu.v, O[dt], 0, 0, 0);
        }
        __builtin_amdgcn_s_setprio(0);
    }

    // reduce l over quads (within wave): lv = sum over this wave's 32 keys
    float lv = l_acc;
    lv += __shfl_xor(lv, 16, 64);
    lv += __shfl_xor(lv, 32, 64);

    // pair-combine: waves 4-7 publish partials; waves 0-3 finalize
    __syncthreads();                         // all tile reads done; reuse LDS
    float* Oscr = reinterpret_cast<float*>(&sK[0][0]);      // 4*64*16 f32 = 16 KB
    float* lscr = reinterpret_cast<float*>(&sVt32[0][0]);   // 4*64 f32
    if (w4 == 1) {
        const int basei = wq * 1024 + lane * 16;
        #pragma unroll
        for (int dt = 0; dt < 4; dt++)
            #pragma unroll
            for (int j = 0; j < 4; j++)
                Oscr[basei + dt * 4 + j] = O[dt][j];
        lscr[wq * 64 + lane] = lv;
    }
    __syncthreads();
    if (w4 == 0) {
        const int basei = wq * 1024 + lane * 16;
        #pragma unroll
        for (int dt = 0; dt < 4; dt++)
            #pragma unroll
            for (int j = 0; j < 4; j++)
                O[dt][j] += Oscr[basei + dt * 4 + j];
        lv += lscr[wq * 64 + lane];
        const float inv = 1.0f / lv;
        const int qrow = qt * 64 + wq * 16 + l16;
        u16* orow = qkvb + bb + (size_t)qrow * QKV_N + h * DHEAD;
        #pragma unroll
        for (int dt = 0; dt < 4; dt++) {
            u32x2 pk;
            pk.x = cvt_pk_bf16(O[dt][0] * inv, O[dt][1] * inv);
            pk.y = cvt_pk_bf16(O[dt][2] * inv, O[dt][3] * inv);
            *reinterpret_cast<u32x2*>(&orow[dt * 16 + quad * 4]) = pk;
        }
    }
}

// ---------------------------------------------------------------------------
extern "C" void kernel_launch(void* const* d_in, const int* in_sizes, int n_in,
                              void* d_out, int out_size, void* d_ws, size_t ws_size,
                              hipStream_t stream)
{
    const float* x      = (const float*)d_in[0];
    const float* cosb   = (const float*)d_in[1];
    const float* sinb   = (const float*)d_in[2];
    const float* qkv_w  = (const float*)d_in[3];
    const float* qkv_b  = (const float*)d_in[4];
    const float* proj_w = (const float*)d_in[5];
    const float* proj_b = (const float*)d_in[6];
    const float* qn_w   = (const float*)d_in[7];
    const float* kn_w   = (const float*)d_in[8];
    float* out = (float*)d_out;

    char* ws = (char*)d_ws;
    u16* qkvb = (u16*)(ws);                    // 4096 x 2304 bf16 = 18,874,368 B
    u16* xb   = (u16*)(ws + 18874368);         // 4096 x 768  bf16 =  6,291,456 B
    u16* wT   = (u16*)(ws + 25165824);         // 2304 x 768  bf16 =  3,538,944 B
    u16* pwT  = (u16*)(ws + 28704768);         //  768 x 768  bf16 =  1,179,648 B

    // 0. fused prep: x->bf16, both weight transposes
    prep_kernel<<<PREP_CONV + PREP_TQ + PREP_TP, 256, 0, stream>>>(
        x, xb, qkv_w, wT, proj_w, pwT);

    // 1. QKV projection + fused RMSNorm/RoPE -> bf16 qkv buffer (dbuf)
    gemm_qkv_mfma_kernel<<<576, 256, 0, stream>>>(
        xb, CDIM, wT, qkv_b, cosb, sinb, qn_w, kn_w, qkvb, QKV_N, CDIM);

    // 2. Flash MFMA attention, 8-wave key-split + permlane P (out -> q slot)
    attn_mfma_kernel<<<dim3(SEQ / 64, HEADS, BATCH), 512, 0, stream>>>(qkvb);

    // 3. Output projection (bf16 MFMA 64x64 BK64, fp32 out)
    gemm_proj_mfma_kernel<<<768, 256, 0, stream>>>(
        qkvb, QKV_N, pwT, proj_b, out, CDIM, CDIM);
}